// Round 5
// baseline (1648.258 us; speedup 1.0000x reference)
//
#include <hip/hip_runtime.h>

#define THREADS 256
#define SPB 16   // 16 samples/block: each 32-lane half-wave owns TWO samples (in-lane ILP)

// fast reciprocal (v_rcp_f32, ~1 ulp)
__device__ __forceinline__ float frcp(float x){ return __builtin_amdgcn_rcpf(x); }
__device__ __forceinline__ float fsig(float x){ return frcp(1.0f + __expf(-x)); }
// tanh = 1 - 2/(e^{2x}+1): saturates correctly at +-inf, no clamp needed
__device__ __forceinline__ float ftanh(float x){
    float e = __expf(2.0f * x);
    return fmaf(-2.0f, frcp(e + 1.0f), 1.0f);
}
// NaN-PROPAGATING leaky relu
__device__ __forceinline__ float lrelu(float x){ return x > 0.0f ? x : 0.01f * x; }

__global__ void diag_kernel(float* outp, float code){ outp[0] = code; }

// 5-step LSTM recurrence for TWO samples per lane (4 gate rows each, shared weights).
// wh rows streamed from global (L1-hot, ~4KB working set) in k-chunks of 4; each
// loaded wh value feeds BOTH samples' FMA chains (8 independent chains -> ILP fills
// the L1/LDS/transcendental stall windows that 2-waves/SIMD occupancy cannot).
// h_t published to hA/hB LDS lines (t*32+j) and broadcast-read as float4 at t+1;
// same-wave lockstep, compiler orders via lgkmcnt. NO barriers in here.
__device__ __forceinline__ void lstm_rec2(const float* __restrict__ whh, int j,
                                          const float (&aA)[5][4], const float (&aB)[5][4],
                                          float* __restrict__ hA, float* __restrict__ hB,
                                          float& s1A, float& s2A, float& s1B, float& s2B)
{
    const float* w0 = whh + (size_t)(0*32 + j)*32;
    const float* w1 = whh + (size_t)(1*32 + j)*32;
    const float* w2 = whh + (size_t)(2*32 + j)*32;
    const float* w3 = whh + (size_t)(3*32 + j)*32;
    float cA = 0.0f, cB = 0.0f;
    s1A = 0.0f; s2A = 0.0f; s1B = 0.0f; s2B = 0.0f;
    #pragma unroll
    for (int t = 0; t < 5; ++t){
        float qA0=aA[t][0], qA1=aA[t][1], qA2=aA[t][2], qA3=aA[t][3];
        float qB0=aB[t][0], qB1=aB[t][1], qB2=aB[t][2], qB3=aB[t][3];
        if (t > 0){
            const float* hpA = hA + (t-1)*32;
            const float* hpB = hB + (t-1)*32;
            #pragma unroll
            for (int k0 = 0; k0 < 32; k0 += 4){
                float4 a  = *(const float4*)(hpA + k0);   // broadcast, conflict-free
                float4 b  = *(const float4*)(hpB + k0);
                float4 u0 = *(const float4*)(w0 + k0);    // L1-hot, imm-offset loads
                float4 u1 = *(const float4*)(w1 + k0);
                float4 u2 = *(const float4*)(w2 + k0);
                float4 u3 = *(const float4*)(w3 + k0);
                qA0 = fmaf(u0.x,a.x,fmaf(u0.y,a.y,fmaf(u0.z,a.z,fmaf(u0.w,a.w,qA0))));
                qB0 = fmaf(u0.x,b.x,fmaf(u0.y,b.y,fmaf(u0.z,b.z,fmaf(u0.w,b.w,qB0))));
                qA1 = fmaf(u1.x,a.x,fmaf(u1.y,a.y,fmaf(u1.z,a.z,fmaf(u1.w,a.w,qA1))));
                qB1 = fmaf(u1.x,b.x,fmaf(u1.y,b.y,fmaf(u1.z,b.z,fmaf(u1.w,b.w,qB1))));
                qA2 = fmaf(u2.x,a.x,fmaf(u2.y,a.y,fmaf(u2.z,a.z,fmaf(u2.w,a.w,qA2))));
                qB2 = fmaf(u2.x,b.x,fmaf(u2.y,b.y,fmaf(u2.z,b.z,fmaf(u2.w,b.w,qB2))));
                qA3 = fmaf(u3.x,a.x,fmaf(u3.y,a.y,fmaf(u3.z,a.z,fmaf(u3.w,a.w,qA3))));
                qB3 = fmaf(u3.x,b.x,fmaf(u3.y,b.y,fmaf(u3.z,b.z,fmaf(u3.w,b.w,qB3))));
            }
        }
        float iA=fsig(qA0), fA=fsig(qA1), gA=ftanh(qA2), oA=fsig(qA3);
        float iB=fsig(qB0), fB=fsig(qB1), gB=ftanh(qB2), oB=fsig(qB3);
        cA = fmaf(fA, cA, iA*gA);
        cB = fmaf(fB, cB, iB*gB);
        float hAv = oA * ftanh(cA);
        float hBv = oB * ftanh(cB);
        s1A += hAv; s2A = fmaf(hAv, hAv, s2A);
        s1B += hBv; s2B = fmaf(hBv, hBv, s2B);
        hA[t*32 + j] = hAv;
        hB[t*32 + j] = hBv;
    }
}

// NOTE (empirical R0-R4): waves/SIMD = floor(256/VGPR); min-waves launch bounds clamp
// VGPR and cause scratch spills (R1). Keep (256,1); manage pressure in source.
// R4 lesson: NEVER put __syncthreads in the recurrence (barrier-serialized, -50%).
__global__ __launch_bounds__(THREADS, 1)
void reslstm_kernel(const float* __restrict__ data,
                    const float* __restrict__ wih0, const float* __restrict__ whh0,
                    const float* __restrict__ bih0, const float* __restrict__ bhh0,
                    const float* __restrict__ g0p,  const float* __restrict__ be0p,
                    const float* __restrict__ wih1, const float* __restrict__ whh1,
                    const float* __restrict__ bih1, const float* __restrict__ bhh1,
                    const float* __restrict__ g1p,  const float* __restrict__ be1p,
                    const float* __restrict__ dwp,  const float* __restrict__ dbp,
                    float* __restrict__ outp, int Btot)
{
    // xs: [s][t][64] input (pad n=62,63=0); per-sample line reused as layer-1 h scratch
    __shared__ __attribute__((aligned(16))) float xs[SPB*320];     // 20 KB
    // wbuf phase A: wih0 [128][68]; phase B: wih1 [128][36] (restaged)
    __shared__ __attribute__((aligned(16))) float wbuf[128*68];    // 34.8 KB
    __shared__ __attribute__((aligned(16))) float out0s[SPB*160];  // 10.2 KB; doubles as layer-0 h lines
    __shared__ float bias0s[128], bias1s[128];
    __shared__ float g0s[160], be0s[160], g1s[160], be1s[160];
    __shared__ float dws[480];
    __shared__ float dbs[3];
    // total ~69.5 KB -> 2 blocks/CU (8 waves/CU), matching the 2-waves/SIMD VGPR limit

    const int tid = threadIdx.x;
    const int b0  = blockIdx.x * SPB;
    const int nsamp = (Btot - b0 < SPB) ? (Btot - b0) : SPB;

    // ---------------- stage (coalesced fp32 global -> LDS) ----------------
    {
        const float* dat = data + (size_t)b0 * 310;   // sample chunk: idx = n*5 + t
        for (int i = tid; i < nsamp*310; i += THREADS){
            int s = i / 310, r = i - s*310;
            int n = r / 5,   t = r - n*5;
            xs[s*320 + t*64 + n] = dat[i];
        }
        for (int i = tid; i < SPB*10; i += THREADS){          // zero pad n=62,63
            int s = i / 10, q = i - s*10;
            xs[s*320 + (q>>1)*64 + 62 + (q&1)] = 0.0f;
        }
        for (int i = tid; i < 128*62; i += THREADS){
            int row = i / 62, n = i - row*62;
            wbuf[row*68 + n] = wih0[i];
        }
        for (int i = tid; i < 128*6; i += THREADS){           // zero pad n=62..67
            int row = i / 6, n = i - row*6;
            wbuf[row*68 + 62 + n] = 0.0f;
        }
        if (tid < 128)  bias0s[tid] = bih0[tid] + bhh0[tid];
        else            { int q = tid - 128; bias1s[q] = bih1[q] + bhh1[q]; }
        if (tid < 160){
            g0s[tid] = g0p[tid];  be0s[tid] = be0p[tid];
            g1s[tid] = g1p[tid];  be1s[tid] = be1p[tid];
        }
        for (int i = tid; i < 480; i += THREADS) dws[i] = dwp[i];
        if (tid < 3) dbs[tid] = dbp[tid];
    }
    __syncthreads();

    const int j  = tid & 31;          // hidden unit owned by this lane
    const int q  = tid >> 5;          // half-wave id 0..7
    const int sA = 2*q, sB = 2*q + 1; // the two samples this lane processes

    float* xA = xs    + sA*320;       // input, later layer-1 h scratch
    float* xB = xs    + sB*320;
    float* oA = out0s + sA*160;       // layer-0 h, then out0 (post LN+lrelu)
    float* oB = out0s + sB*160;

    // ---------------- phase A: xg = x @ W_ih0^T + biases, both samples ----------------
    float aA[5][4], aB[5][4];
    #pragma unroll
    for (int r = 0; r < 4; ++r){
        float bv = bias0s[r*32 + j];
        #pragma unroll
        for (int t = 0; t < 5; ++t){ aA[t][r] = bv; aB[t][r] = bv; }
    }
    {
        const float* wp = wbuf + j*68;
        #pragma unroll 4
        for (int n0 = 0; n0 < 64; n0 += 4){
            float4 w0 = *(const float4*)(wp            + n0);  // w loaded ONCE,
            float4 w1 = *(const float4*)(wp + 1*32*68 + n0);   // used for BOTH samples
            float4 w2 = *(const float4*)(wp + 2*32*68 + n0);
            float4 w3 = *(const float4*)(wp + 3*32*68 + n0);
            #pragma unroll
            for (int t = 0; t < 5; ++t){
                float4 va = *(const float4*)(xA + t*64 + n0);  // half-wave broadcast
                float4 vb = *(const float4*)(xB + t*64 + n0);
                aA[t][0] = fmaf(w0.x,va.x,fmaf(w0.y,va.y,fmaf(w0.z,va.z,fmaf(w0.w,va.w,aA[t][0]))));
                aB[t][0] = fmaf(w0.x,vb.x,fmaf(w0.y,vb.y,fmaf(w0.z,vb.z,fmaf(w0.w,vb.w,aB[t][0]))));
                aA[t][1] = fmaf(w1.x,va.x,fmaf(w1.y,va.y,fmaf(w1.z,va.z,fmaf(w1.w,va.w,aA[t][1]))));
                aB[t][1] = fmaf(w1.x,vb.x,fmaf(w1.y,vb.y,fmaf(w1.z,vb.z,fmaf(w1.w,vb.w,aB[t][1]))));
                aA[t][2] = fmaf(w2.x,va.x,fmaf(w2.y,va.y,fmaf(w2.z,va.z,fmaf(w2.w,va.w,aA[t][2]))));
                aB[t][2] = fmaf(w2.x,vb.x,fmaf(w2.y,vb.y,fmaf(w2.z,vb.z,fmaf(w2.w,vb.w,aB[t][2]))));
                aA[t][3] = fmaf(w3.x,va.x,fmaf(w3.y,va.y,fmaf(w3.z,va.z,fmaf(w3.w,va.w,aA[t][3]))));
                aB[t][3] = fmaf(w3.x,vb.x,fmaf(w3.y,vb.y,fmaf(w3.z,vb.z,fmaf(w3.w,vb.w,aB[t][3]))));
            }
        }
    }

    // ---------------- layer 0 recurrence + LN + LeakyReLU (both samples) ----------------
    {
        float s1A, s2A, s1B, s2B;
        lstm_rec2(whh0, j, aA, aB, oA, oB, s1A, s2A, s1B, s2B);
        #pragma unroll
        for (int m = 1; m < 32; m <<= 1){
            s1A += __shfl_xor(s1A, m, 64);  s2A += __shfl_xor(s2A, m, 64);
            s1B += __shfl_xor(s1B, m, 64);  s2B += __shfl_xor(s2B, m, 64);
        }
        float muA = s1A*(1.0f/160.0f), muB = s1B*(1.0f/160.0f);
        float rsA = rsqrtf(s2A*(1.0f/160.0f) - muA*muA + 1e-5f);
        float rsB = rsqrtf(s2B*(1.0f/160.0f) - muB*muB + 1e-5f);
        #pragma unroll
        for (int t = 0; t < 5; ++t){
            int ix = t*32 + j;
            float gv = g0s[ix], bv = be0s[ix];
            float vA = oA[ix];
            oA[ix] = lrelu(fmaf((vA - muA)*rsA, gv, bv));
            float vB = oB[ix];
            oB[ix] = lrelu(fmaf((vB - muB)*rsB, gv, bv));
        }
    }

    __syncthreads();
    // ---------------- restage wih1 into wbuf [128][36] ----------------
    for (int i = tid; i < 128*32; i += THREADS){
        int row = i >> 5, k = i & 31;
        wbuf[row*36 + k] = wih1[i];
    }
    for (int i = tid; i < 128*4; i += THREADS){
        int row = i >> 2;
        wbuf[row*36 + 32 + (i & 3)] = 0.0f;
    }
    __syncthreads();

    // ---------------- phase B: xg1 = out0 @ W_ih1^T + biases ----------------
    #pragma unroll
    for (int r = 0; r < 4; ++r){
        float bv = bias1s[r*32 + j];
        #pragma unroll
        for (int t = 0; t < 5; ++t){ aA[t][r] = bv; aB[t][r] = bv; }
    }
    {
        const float* wp = wbuf + j*36;
        #pragma unroll 2
        for (int k0 = 0; k0 < 32; k0 += 4){
            float4 w0 = *(const float4*)(wp            + k0);
            float4 w1 = *(const float4*)(wp + 1*32*36 + k0);
            float4 w2 = *(const float4*)(wp + 2*32*36 + k0);
            float4 w3 = *(const float4*)(wp + 3*32*36 + k0);
            #pragma unroll
            for (int t = 0; t < 5; ++t){
                float4 va = *(const float4*)(oA + t*32 + k0);
                float4 vb = *(const float4*)(oB + t*32 + k0);
                aA[t][0] = fmaf(w0.x,va.x,fmaf(w0.y,va.y,fmaf(w0.z,va.z,fmaf(w0.w,va.w,aA[t][0]))));
                aB[t][0] = fmaf(w0.x,vb.x,fmaf(w0.y,vb.y,fmaf(w0.z,vb.z,fmaf(w0.w,vb.w,aB[t][0]))));
                aA[t][1] = fmaf(w1.x,va.x,fmaf(w1.y,va.y,fmaf(w1.z,va.z,fmaf(w1.w,va.w,aA[t][1]))));
                aB[t][1] = fmaf(w1.x,vb.x,fmaf(w1.y,vb.y,fmaf(w1.z,vb.z,fmaf(w1.w,vb.w,aB[t][1]))));
                aA[t][2] = fmaf(w2.x,va.x,fmaf(w2.y,va.y,fmaf(w2.z,va.z,fmaf(w2.w,va.w,aA[t][2]))));
                aB[t][2] = fmaf(w2.x,vb.x,fmaf(w2.y,vb.y,fmaf(w2.z,vb.z,fmaf(w2.w,vb.w,aB[t][2]))));
                aA[t][3] = fmaf(w3.x,va.x,fmaf(w3.y,va.y,fmaf(w3.z,va.z,fmaf(w3.w,va.w,aA[t][3]))));
                aB[t][3] = fmaf(w3.x,vb.x,fmaf(w3.y,vb.y,fmaf(w3.z,vb.z,fmaf(w3.w,vb.w,aB[t][3]))));
            }
        }
    }

    // ---------------- layer 1 recurrence + LN + residual + head ----------------
    float p0A=0.f,p1A=0.f,p2A=0.f, p0B=0.f,p1B=0.f,p2B=0.f;
    {
        float s1A, s2A, s1B, s2B;
        lstm_rec2(whh1, j, aA, aB, xA, xB, s1A, s2A, s1B, s2B);  // xs lines reused
        #pragma unroll
        for (int m = 1; m < 32; m <<= 1){
            s1A += __shfl_xor(s1A, m, 64);  s2A += __shfl_xor(s2A, m, 64);
            s1B += __shfl_xor(s1B, m, 64);  s2B += __shfl_xor(s2B, m, 64);
        }
        float muA = s1A*(1.0f/160.0f), muB = s1B*(1.0f/160.0f);
        float rsA = rsqrtf(s2A*(1.0f/160.0f) - muA*muA + 1e-5f);
        float rsB = rsqrtf(s2B*(1.0f/160.0f) - muB*muB + 1e-5f);
        #pragma unroll
        for (int t = 0; t < 5; ++t){
            int ix = t*32 + j;
            float gv = g1s[ix], bv = be1s[ix];
            float d0 = dws[ix], d1 = dws[160+ix], d2 = dws[320+ix];
            float vA = xA[ix];
            float yA = lrelu(fmaf((vA - muA)*rsA, gv, bv)) + oA[ix];   // residual
            p0A = fmaf(d0, yA, p0A); p1A = fmaf(d1, yA, p1A); p2A = fmaf(d2, yA, p2A);
            float vB = xB[ix];
            float yB = lrelu(fmaf((vB - muB)*rsB, gv, bv)) + oB[ix];
            p0B = fmaf(d0, yB, p0B); p1B = fmaf(d1, yB, p1B); p2B = fmaf(d2, yB, p2B);
        }
    }
    #pragma unroll
    for (int m = 1; m < 32; m <<= 1){
        p0A += __shfl_xor(p0A, m, 64);  p1A += __shfl_xor(p1A, m, 64);  p2A += __shfl_xor(p2A, m, 64);
        p0B += __shfl_xor(p0B, m, 64);  p1B += __shfl_xor(p1B, m, 64);  p2B += __shfl_xor(p2B, m, 64);
    }
    if (j < 3){
        if (sA < nsamp){
            float v = (j == 0) ? p0A : ((j == 1) ? p1A : p2A);
            outp[(size_t)(b0 + sA)*3 + j] = lrelu(v + dbs[j]);
        }
        if (sB < nsamp){
            float v = (j == 0) ? p0B : ((j == 1) ? p1B : p2B);
            outp[(size_t)(b0 + sB)*3 + j] = lrelu(v + dbs[j]);
        }
    }
}

extern "C" void kernel_launch(void* const* d_in, const int* in_sizes, int n_in,
                              void* d_out, int out_size, void* d_ws, size_t ws_size,
                              hipStream_t stream)
{
    (void)d_ws; (void)ws_size;

    const int B = out_size / 3;

    // Locate 'data' = largest input; infer the harness's input ordering from it.
    int idx_data = 0;
    for (int i = 1; i < n_in; ++i)
        if (in_sizes[i] > in_sizes[idx_data]) idx_data = i;

    // semantic slots (reference dict order):
    // 0 data,1 wih0,2 whh0,3 bih0,4 bhh0,5 g0,6 be0,7 wih1,8 whh1,9 bih1,
    // 10 bhh1,11 g1,12 be1,13 dw,14 db
    static const int dict_map[15]  = {0,1,2,3,4,5,6,7,8,9,10,11,12,13,14};
    // alphabetical key order fallback
    static const int alpha_map[15] = {6,13,11,2,0,9,4,14,12,3,1,10,5,8,7};
    static const int rev_map[15]   = {14,13,12,11,10,9,8,7,6,5,4,3,2,1,0};

    const int* map = dict_map;
    if (idx_data == 6)       map = alpha_map;
    else if (idx_data == 14) map = rev_map;

    long ds  = (long)in_sizes[idx_data];
    long ws0 = (long)in_sizes[map[1]];
    bool ok = (ds == (long)B*310 || ds == (long)B*620 || ds == (long)B*1240)
           && (ws0 == 7936 || ws0 == 15872 || ws0 == 31744);

    if (!ok || B <= 0){
        diag_kernel<<<1, 1, 0, stream>>>((float*)d_out, 100.0f + 10.0f*idx_data);
        return;
    }

    const float* P[15];
    for (int k = 0; k < 15; ++k) P[k] = (const float*)d_in[map[k]];

    const int nblocks = (B + SPB - 1) / SPB;
    reslstm_kernel<<<dim3(nblocks), dim3(THREADS), 0, stream>>>(
        P[0], P[1], P[2], P[3], P[4], P[5], P[6], P[7], P[8], P[9],
        P[10], P[11], P[12], P[13], P[14],
        (float*)d_out, B);
}

// Round 6
// 1040.352 us; speedup vs baseline: 1.5843x; 1.5843x over previous
//
#include <hip/hip_runtime.h>
#include <hip/hip_bf16.h>

#define THREADS 256
#define SPB 8   // samples per block, one per 32-lane half-wave

// fast reciprocal (v_rcp_f32, ~1 ulp). Without fast-math, '/' emits the IEEE
// v_div_scale/v_div_fmas/v_div_fixup sequence (~10 dependent VALU ops) — on the
// serial activation chain of the recurrence that is pure critical-path cost.
__device__ __forceinline__ float frcp(float x){ return __builtin_amdgcn_rcpf(x); }
__device__ __forceinline__ float fsig(float x){ return frcp(1.0f + __expf(-x)); }
// tanh = 1 - 2/(e^{2x}+1): e->inf gives 1, e->0 gives -1; saturates, no clamp needed
__device__ __forceinline__ float ftanh(float x){
    float e = __expf(2.0f * x);
    return fmaf(-2.0f, frcp(e + 1.0f), 1.0f);
}
// NaN-PROPAGATING leaky relu (fmaxf/fminf would flush NaN to 0 and mask bugs)
__device__ __forceinline__ float lrelu(float x){
    return x > 0.0f ? x : 0.01f * x;
}

__global__ void diag_kernel(float* outp, float code){
    outp[0] = code;
}

// load per-lane W_hh rows {j, 32+j, 64+j, 96+j} straight from global (L1-hot) as float4
__device__ __forceinline__ void load_wh_global(const float* __restrict__ whh, int j, float (&wh)[4][32]){
    #pragma unroll
    for (int r = 0; r < 4; ++r){
        const float* rp = whh + (r*32 + j)*32;
        #pragma unroll
        for (int q = 0; q < 8; ++q){
            float4 v = *(const float4*)(rp + q*4);
            wh[r][q*4+0] = v.x; wh[r][q*4+1] = v.y;
            wh[r][q*4+2] = v.z; wh[r][q*4+3] = v.w;
        }
    }
}

// 5-step LSTM recurrence; acc = gate pre-activations (xg + biases); h broadcast via
// half-wave shuffle (pure VALU/DS-issue — measured better than LDS round-trip at
// 2 waves/SIMD occupancy; R2 regression).
__device__ __forceinline__ void lstm_rec(const float (&wh)[4][32], const float (&acc)[5][4],
                                         float (&out)[5]){
    float h = 0.0f, c = 0.0f;
    #pragma unroll
    for (int t = 0; t < 5; ++t){
        float q0 = acc[t][0], q1 = acc[t][1], q2 = acc[t][2], q3 = acc[t][3];
        if (t > 0){
            #pragma unroll
            for (int k = 0; k < 32; ++k){
                float hk = __shfl(h, k, 32);   // broadcast h_k within the 32-lane half-wave
                q0 = fmaf(wh[0][k], hk, q0);
                q1 = fmaf(wh[1][k], hk, q1);
                q2 = fmaf(wh[2][k], hk, q2);
                q3 = fmaf(wh[3][k], hk, q3);
            }
        }
        float iv = fsig(q0), fv = fsig(q1), gv = ftanh(q2), ov = fsig(q3);
        c = fmaf(fv, c, iv * gv);
        h = ov * ftanh(c);
        out[t] = h;
    }
}

// LayerNorm over (T,H)=160 jointly + LeakyReLU, in place
__device__ __forceinline__ void ln_lrelu(float (&o)[5], const float* gs, const float* bs, int j){
    float s1 = 0.0f, s2 = 0.0f;
    #pragma unroll
    for (int t = 0; t < 5; ++t){ s1 += o[t]; s2 = fmaf(o[t], o[t], s2); }
    #pragma unroll
    for (int m = 1; m < 32; m <<= 1){
        s1 += __shfl_xor(s1, m, 64);   // masks <32 stay within the half-wave
        s2 += __shfl_xor(s2, m, 64);
    }
    float mu   = s1 * (1.0f/160.0f);
    float var  = s2 * (1.0f/160.0f) - mu*mu;
    float rstd = rsqrtf(var + 1e-5f);
    #pragma unroll
    for (int t = 0; t < 5; ++t){
        float y = (o[t] - mu) * rstd;
        y = fmaf(y, gs[t*32 + j], bs[t*32 + j]);
        o[t] = lrelu(y);
    }
}

// Empirical occupancy model (R0-R5): waves/SIMD = floor(256/VGPR_Count).
// Do NOT set a min-waves bound: (256,4) clamps to 64 VGPR -> scratch spill (R1, R5-like).
// Do NOT add barriers or LDS round-trips to the recurrence (R4: -50%, R2: -7%).
// Do NOT grow per-lane state for multi-sample ILP (R5: 256 VGPR, spills).
__global__ __launch_bounds__(THREADS, 1)
void reslstm_kernel(const float* __restrict__ data,
                    const float* __restrict__ wih0, const float* __restrict__ whh0,
                    const float* __restrict__ bih0, const float* __restrict__ bhh0,
                    const float* __restrict__ g0p,  const float* __restrict__ be0p,
                    const float* __restrict__ wih1, const float* __restrict__ whh1,
                    const float* __restrict__ bih1, const float* __restrict__ bhh1,
                    const float* __restrict__ g1p,  const float* __restrict__ be1p,
                    const float* __restrict__ dwp,  const float* __restrict__ dbp,
                    float* __restrict__ outp, int Btot)
{
    // xs: [s][t][64], pad n=62,63 with 0; reads are half-wave broadcasts (no conflicts)
    __shared__ __attribute__((aligned(16))) float xs[SPB*320];
    // wbuf phase A: wih0 [128][68] (stride 68 floats = 272 B, 16B-aligned; 4-way bank alias max)
    // wbuf phase B: wih1 [128][36] (stride 36 floats = 144 B, 16B-aligned)
    __shared__ __attribute__((aligned(16))) float wbuf[128*68];
    __shared__ __attribute__((aligned(16))) float out0s[SPB*160];
    __shared__ float bias0s[128], bias1s[128];
    __shared__ float g0s[160], be0s[160], g1s[160], be1s[160];
    __shared__ float dws[480];
    __shared__ float dbs[3];

    const int tid = threadIdx.x;
    const int b0  = blockIdx.x * SPB;
    const int nsamp = (Btot - b0 < SPB) ? (Btot - b0) : SPB;

    // ---------------- stage (coalesced fp32 global -> LDS) ----------------
    {
        const float* dat = data + (size_t)b0 * 310;   // sample chunk: idx = n*5 + t
        for (int i = tid; i < nsamp*310; i += THREADS){
            int s = i / 310, r = i - s*310;
            int n = r / 5,   t = r - n*5;
            xs[s*320 + t*64 + n] = dat[i];
        }
        for (int i = tid; i < SPB*10; i += THREADS){          // zero pad n=62,63
            int s = i / 10, q = i - s*10;
            xs[s*320 + (q>>1)*64 + 62 + (q&1)] = 0.0f;
        }
        for (int i = tid; i < 128*62; i += THREADS){
            int row = i / 62, n = i - row*62;
            wbuf[row*68 + n] = wih0[i];
        }
        for (int i = tid; i < 128*6; i += THREADS){           // zero pad n=62..67
            int row = i / 6, n = i - row*6;
            wbuf[row*68 + 62 + n] = 0.0f;
        }
        if (tid < 128)  bias0s[tid] = bih0[tid] + bhh0[tid];
        else            { int q = tid - 128; bias1s[q] = bih1[q] + bhh1[q]; }
        if (tid < 160){
            g0s[tid] = g0p[tid];  be0s[tid] = be0p[tid];
            g1s[tid] = g1p[tid];  be1s[tid] = be1p[tid];
        }
        for (int i = tid; i < 480; i += THREADS) dws[i] = dwp[i];
        if (tid < 3) dbs[tid] = dbp[tid];
    }
    __syncthreads();

    const int j = tid & 31;       // hidden unit owned by this lane
    const int s = tid >> 5;       // sample-in-block (half-wave)

    // ---------------- phase A: xg0 = x @ W_ih0^T + biases (float4 LDS reads) ----------------
    float acc[5][4];
    #pragma unroll
    for (int r = 0; r < 4; ++r){
        float bv = bias0s[r*32 + j];
        #pragma unroll
        for (int t = 0; t < 5; ++t) acc[t][r] = bv;
    }
    {
        const float* xp  = xs   + s*320;
        const float* wp0 = wbuf + j*68;
        #pragma unroll 4
        for (int n0 = 0; n0 < 64; n0 += 4){
            float4 w[4];
            #pragma unroll
            for (int r = 0; r < 4; ++r)
                w[r] = *(const float4*)(wp0 + r*32*68 + n0);
            #pragma unroll
            for (int t = 0; t < 5; ++t){
                float4 xv = *(const float4*)(xp + t*64 + n0);
                #pragma unroll
                for (int r = 0; r < 4; ++r)
                    acc[t][r] = fmaf(w[r].x, xv.x, fmaf(w[r].y, xv.y, fmaf(w[r].z, xv.z, fmaf(w[r].w, xv.w, acc[t][r]))));
            }
        }
    }

    // ---------------- layer 0 recurrence + LN + LeakyReLU ----------------
    float o0[5];
    {
        float wh[4][32];
        load_wh_global(whh0, j, wh);
        lstm_rec(wh, acc, o0);
    }
    ln_lrelu(o0, g0s, be0s, j);
    #pragma unroll
    for (int t = 0; t < 5; ++t) out0s[s*160 + t*32 + j] = o0[t];

    __syncthreads();
    // ---------------- restage wih1 into wbuf [128][36] ----------------
    for (int i = tid; i < 128*32; i += THREADS){
        int row = i >> 5, k = i & 31;
        wbuf[row*36 + k] = wih1[i];
    }
    for (int i = tid; i < 128*4; i += THREADS){
        int row = i >> 2;
        wbuf[row*36 + 32 + (i & 3)] = 0.0f;
    }
    __syncthreads();

    // ---------------- phase B: xg1 = out0 @ W_ih1^T + biases ----------------
    #pragma unroll
    for (int r = 0; r < 4; ++r){
        float bv = bias1s[r*32 + j];
        #pragma unroll
        for (int t = 0; t < 5; ++t) acc[t][r] = bv;
    }
    {
        const float* wp1 = wbuf  + j*36;
        const float* op  = out0s + s*160;
        #pragma unroll 2
        for (int k0 = 0; k0 < 32; k0 += 4){
            float4 w[4];
            #pragma unroll
            for (int r = 0; r < 4; ++r)
                w[r] = *(const float4*)(wp1 + r*32*36 + k0);
            #pragma unroll
            for (int t = 0; t < 5; ++t){
                float4 ov = *(const float4*)(op + t*32 + k0);
                #pragma unroll
                for (int r = 0; r < 4; ++r)
                    acc[t][r] = fmaf(w[r].x, ov.x, fmaf(w[r].y, ov.y, fmaf(w[r].z, ov.z, fmaf(w[r].w, ov.w, acc[t][r]))));
            }
        }
    }

    // ---------------- layer 1 recurrence + LN + residual ----------------
    float o1[5];
    {
        float wh[4][32];
        load_wh_global(whh1, j, wh);
        lstm_rec(wh, acc, o1);
    }
    ln_lrelu(o1, g1s, be1s, j);
    #pragma unroll
    for (int t = 0; t < 5; ++t) o1[t] += o0[t];   // residual

    // ---------------- dense head: (B,160) @ dw^T + db, LeakyReLU ----------------
    float p0 = 0.0f, p1 = 0.0f, p2 = 0.0f;
    #pragma unroll
    for (int t = 0; t < 5; ++t){
        float v = o1[t];
        p0 = fmaf(dws[      t*32 + j], v, p0);
        p1 = fmaf(dws[160 + t*32 + j], v, p1);
        p2 = fmaf(dws[320 + t*32 + j], v, p2);
    }
    #pragma unroll
    for (int m = 1; m < 32; m <<= 1){
        p0 += __shfl_xor(p0, m, 64);
        p1 += __shfl_xor(p1, m, 64);
        p2 += __shfl_xor(p2, m, 64);
    }
    if (j < 3 && s < nsamp){
        float v = (j == 0) ? p0 : ((j == 1) ? p1 : p2);
        v = lrelu(v + dbs[j]);
        outp[(size_t)(b0 + s)*3 + j] = v;
    }
}

extern "C" void kernel_launch(void* const* d_in, const int* in_sizes, int n_in,
                              void* d_out, int out_size, void* d_ws, size_t ws_size,
                              hipStream_t stream)
{
    (void)d_ws; (void)ws_size;

    const int B = out_size / 3;

    // Locate 'data' = largest input; infer the harness's input ordering from it.
    int idx_data = 0;
    for (int i = 1; i < n_in; ++i)
        if (in_sizes[i] > in_sizes[idx_data]) idx_data = i;

    // semantic slots (reference dict order):
    // 0 data,1 wih0,2 whh0,3 bih0,4 bhh0,5 g0,6 be0,7 wih1,8 whh1,9 bih1,
    // 10 bhh1,11 g1,12 be1,13 dw,14 db
    static const int dict_map[15]  = {0,1,2,3,4,5,6,7,8,9,10,11,12,13,14};
    // alphabetical key order fallback
    static const int alpha_map[15] = {6,13,11,2,0,9,4,14,12,3,1,10,5,8,7};
    static const int rev_map[15]   = {14,13,12,11,10,9,8,7,6,5,4,3,2,1,0};

    const int* map = dict_map;
    if (idx_data == 6)       map = alpha_map;
    else if (idx_data == 14) map = rev_map;

    long ds  = (long)in_sizes[idx_data];
    long ws0 = (long)in_sizes[map[1]];
    bool ok = (ds == (long)B*310 || ds == (long)B*620 || ds == (long)B*1240)
           && (ws0 == 7936 || ws0 == 15872 || ws0 == 31744);

    if (!ok || B <= 0){
        diag_kernel<<<1, 1, 0, stream>>>((float*)d_out, 100.0f + 10.0f*idx_data);
        return;
    }

    const float* P[15];
    for (int k = 0; k < 15; ++k) P[k] = (const float*)d_in[map[k]];

    const int nblocks = (B + SPB - 1) / SPB;
    reslstm_kernel<<<dim3(nblocks), dim3(THREADS), 0, stream>>>(
        P[0], P[1], P[2], P[3], P[4], P[5], P[6], P[7], P[8], P[9],
        P[10], P[11], P[12], P[13], P[14],
        (float*)d_out, B);
}